// Round 1
// baseline (16851.750 us; speedup 1.0000x reference)
//
#include <hip/hip_runtime.h>
#include <hip/hip_bf16.h>
#include <math.h>

// ---------------------------------------------------------------------------
// Transformer forward, fp32 everywhere (round 0: correctness baseline).
// B=4 S=1024 D=1024 H=8 Dh=128 F=2048 L=4 V=32000
// ---------------------------------------------------------------------------

#define D_MODEL 1024
#define SEQ     1024
#define BATCH   4
#define NHEAD   8
#define HDIM    128
#define FFN     2048
#define NLAYER  4
#define VOCAB   32000
#define MROWS   (BATCH*SEQ)   // 4096

// ---------------- embedding gather ----------------
__global__ __launch_bounds__(256) void embed_kernel(
    const int* __restrict__ tokens, const float* __restrict__ emb,
    float* __restrict__ X)
{
    int row = blockIdx.x;                  // 0..4095
    int t = tokens[row];
    const float4* src = (const float4*)(emb + (size_t)t * D_MODEL);
    float4* dst = (float4*)(X + (size_t)row * D_MODEL);
    dst[threadIdx.x] = src[threadIdx.x];   // 256 * 4 = 1024 floats
}

// ---------------- layernorm ----------------
__global__ __launch_bounds__(256) void ln_kernel(
    const float* __restrict__ X, const float* __restrict__ g,
    const float* __restrict__ b, float* __restrict__ Y)
{
    __shared__ float red[8];
    int row = blockIdx.x;
    const float4* x4 = (const float4*)(X + (size_t)row * D_MODEL);
    float4 v = x4[threadIdx.x];
    float s  = v.x + v.y + v.z + v.w;
    float ss = v.x*v.x + v.y*v.y + v.z*v.z + v.w*v.w;
    #pragma unroll
    for (int o = 32; o > 0; o >>= 1) { s += __shfl_down(s, o); ss += __shfl_down(ss, o); }
    int wid = threadIdx.x >> 6;
    if ((threadIdx.x & 63) == 0) { red[wid] = s; red[wid + 4] = ss; }
    __syncthreads();
    float tot  = red[0] + red[1] + red[2] + red[3];
    float tot2 = red[4] + red[5] + red[6] + red[7];
    float mu  = tot * (1.0f / D_MODEL);
    float var = tot2 * (1.0f / D_MODEL) - mu * mu;
    float r = rsqrtf(var + 1e-5f);
    const float4* g4 = (const float4*)g;
    const float4* b4 = (const float4*)b;
    float4 gv = g4[threadIdx.x], bv = b4[threadIdx.x];
    float4 o;
    o.x = (v.x - mu) * r * gv.x + bv.x;
    o.y = (v.y - mu) * r * gv.y + bv.y;
    o.z = (v.z - mu) * r * gv.z + bv.z;
    o.w = (v.w - mu) * r * gv.w + bv.w;
    float4* y4 = (float4*)(Y + (size_t)row * D_MODEL);
    y4[threadIdx.x] = o;
}

// ---------------- generic fp32 GEMM, 64x64 tile, 256 thr, 4x4/thread --------
// C[M,N] = act(A[M,K] @ B[K,N] + bias[N]) (+ C if BETA)
// ACT: 0 = none, 1 = exact gelu
__device__ inline float gelu_exact(float x) {
    return 0.5f * x * (1.0f + erff(x * 0.70710678118654752f));
}

template<int ACT, int BETA>
__global__ __launch_bounds__(256) void gemm64(
    const float* __restrict__ A, const float* __restrict__ B,
    const float* __restrict__ bias, float* __restrict__ C,
    int M, int N, int K)
{
    __shared__ float As[16][64];
    __shared__ float Bs[16][64];
    int n0 = blockIdx.x * 64;
    int m0 = blockIdx.y * 64;
    int tid = threadIdx.x;
    int tx = tid & 15, ty = tid >> 4;
    float acc[4][4] = {};
    for (int k0 = 0; k0 < K; k0 += 16) {
        #pragma unroll
        for (int r = 0; r < 4; ++r) {
            int idx = tid + r * 256;           // 0..1023
            int m = idx >> 4, k = idx & 15;
            As[k][m] = A[(size_t)(m0 + m) * K + k0 + k];
        }
        #pragma unroll
        for (int r = 0; r < 4; ++r) {
            int idx = tid + r * 256;
            int k = idx >> 6, n = idx & 63;
            Bs[k][n] = B[(size_t)(k0 + k) * N + n0 + n];
        }
        __syncthreads();
        #pragma unroll
        for (int k = 0; k < 16; ++k) {
            float a[4], bb[4];
            #pragma unroll
            for (int i = 0; i < 4; ++i) a[i] = As[k][ty * 4 + i];
            #pragma unroll
            for (int j = 0; j < 4; ++j) bb[j] = Bs[k][tx * 4 + j];
            #pragma unroll
            for (int i = 0; i < 4; ++i)
                #pragma unroll
                for (int j = 0; j < 4; ++j)
                    acc[i][j] += a[i] * bb[j];
        }
        __syncthreads();
    }
    #pragma unroll
    for (int i = 0; i < 4; ++i) {
        int m = m0 + ty * 4 + i;
        #pragma unroll
        for (int j = 0; j < 4; ++j) {
            int n = n0 + tx * 4 + j;
            float v = acc[i][j] + bias[n];
            if (ACT == 1) v = gelu_exact(v);
            size_t off = (size_t)m * N + n;
            if (BETA) C[off] += v; else C[off] = v;
        }
    }
}

// ---------------- RoPE (in-place on Q,K inside QKV buffer) ----------------
__global__ __launch_bounds__(256) void rope_kernel(float* __restrict__ QKV)
{
    int m = blockIdx.x;            // b*SEQ + s
    int s = m & (SEQ - 1);
    float* rowbase = QKV + (size_t)m * (3 * D_MODEL);
    #pragma unroll
    for (int r = 0; r < 4; ++r) {
        int it = threadIdx.x + r * 256;   // 0..1023
        int qk = it >> 9;                 // 0 = Q, 1 = K
        int rem = it & 511;
        int h = rem >> 6;
        int p = rem & 63;
        // inv_freq = 10000^(-p/64) = exp(-p * ln(10000)/64)
        float inv = expf(-0.1439115683121281f * (float)p);
        float ang = (float)s * inv;
        float sn, c;
        sincosf(ang, &sn, &c);
        float* base = rowbase + qk * D_MODEL + h * HDIM + p;
        float x1 = base[0], x2 = base[64];
        base[0]  = x1 * c - x2 * sn;
        base[64] = x2 * c + x1 * sn;
    }
}

// ---------------- causal attention, one block per (b,h,query i) ------------
__global__ __launch_bounds__(256) void attn_kernel(
    const float* __restrict__ QKV, float* __restrict__ Y)
{
    __shared__ __align__(16) float q[HDIM];
    __shared__ float sp[SEQ];
    __shared__ float red[8];
    int bid = blockIdx.x;
    int i = bid & (SEQ - 1);
    int h = (bid >> 10) & (NHEAD - 1);
    int b = bid >> 13;
    const float* qrow = QKV + ((size_t)(b * SEQ + i)) * (3 * D_MODEL) + h * HDIM;
    if (threadIdx.x < HDIM) q[threadIdx.x] = qrow[threadIdx.x];
    __syncthreads();

    const float scale = 0.08838834764831845f;  // 1/sqrt(128)
    const float* Kbase = QKV + (size_t)b * SEQ * (3 * D_MODEL) + D_MODEL + h * HDIM;
    const float4* q4 = (const float4*)q;

    // phase 1: scores
    float lmax = -INFINITY;
    for (int j = threadIdx.x; j <= i; j += 256) {
        const float4* k4 = (const float4*)(Kbase + (size_t)j * (3 * D_MODEL));
        float d = 0.0f;
        #pragma unroll
        for (int dd = 0; dd < HDIM / 4; ++dd) {
            float4 kv = k4[dd]; float4 qv = q4[dd];
            d += qv.x * kv.x + qv.y * kv.y + qv.z * kv.z + qv.w * kv.w;
        }
        d *= scale;
        sp[j] = d;
        lmax = fmaxf(lmax, d);
    }
    // block max
    #pragma unroll
    for (int o = 32; o > 0; o >>= 1) lmax = fmaxf(lmax, __shfl_down(lmax, o));
    if ((threadIdx.x & 63) == 0) red[threadIdx.x >> 6] = lmax;
    __syncthreads();
    float m = fmaxf(fmaxf(red[0], red[1]), fmaxf(red[2], red[3]));

    // exp + sum (each thread only touches its own sp entries)
    float lsum = 0.0f;
    for (int j = threadIdx.x; j <= i; j += 256) {
        float p = expf(sp[j] - m);
        sp[j] = p;
        lsum += p;
    }
    #pragma unroll
    for (int o = 32; o > 0; o >>= 1) lsum += __shfl_down(lsum, o);
    __syncthreads();   // sp writes visible; red reusable
    if ((threadIdx.x & 63) == 0) red[threadIdx.x >> 6] = lsum;
    __syncthreads();
    float l = red[0] + red[1] + red[2] + red[3];

    // phase 2: ctx[d] = sum_j p[j] * V[j][d]
    if (threadIdx.x < HDIM) {
        int d = threadIdx.x;
        const float* Vbase = QKV + (size_t)b * SEQ * (3 * D_MODEL) + 2 * D_MODEL + h * HDIM + d;
        float acc = 0.0f;
        for (int j = 0; j <= i; ++j)
            acc += sp[j] * Vbase[(size_t)j * (3 * D_MODEL)];
        Y[((size_t)(b * SEQ + i)) * D_MODEL + h * HDIM + d] = acc / l;
    }
}

// ---------------------------------------------------------------------------
extern "C" void kernel_launch(void* const* d_in, const int* in_sizes, int n_in,
                              void* d_out, int out_size, void* d_ws, size_t ws_size,
                              hipStream_t stream)
{
    const int*   tokens = (const int*)  d_in[0];
    const float* emb    = (const float*)d_in[1];
    const float* Wqkv   = (const float*)d_in[2];
    const float* bqkv   = (const float*)d_in[3];
    const float* Wo     = (const float*)d_in[4];
    const float* bo     = (const float*)d_in[5];
    const float* ln1_g  = (const float*)d_in[6];
    const float* ln1_b  = (const float*)d_in[7];
    const float* ln2_g  = (const float*)d_in[8];
    const float* ln2_b  = (const float*)d_in[9];
    const float* W1     = (const float*)d_in[10];
    const float* b1     = (const float*)d_in[11];
    const float* W2     = (const float*)d_in[12];
    const float* b2     = (const float*)d_in[13];
    const float* lnf_g  = (const float*)d_in[14];
    const float* lnf_b  = (const float*)d_in[15];
    const float* Wout   = (const float*)d_in[16];
    const float* bout   = (const float*)d_in[17];
    float* out = (float*)d_out;

    char* ws = (char*)d_ws;
    float* X   = (float*)ws;                              // 4096x1024 (16.8 MB)
    float* Y   = (float*)(ws + 16777216);                 // 4096x1024
    float* QKV = (float*)(ws + 33554432);                 // 4096x3072 (50.3 MB)
    float* Z   = QKV;                                     // 4096x1024 (aliases QKV)
    float* FF  = (float*)(ws + 33554432 + 16777216);      // 4096x2048 (aliases QKV tail)

    const int M = MROWS, Dm = D_MODEL, F = FFN, V = VOCAB;

    embed_kernel<<<MROWS, 256, 0, stream>>>(tokens, emb, X);

    for (int L = 0; L < NLAYER; ++L) {
        ln_kernel<<<MROWS, 256, 0, stream>>>(X, ln1_g + (size_t)L * Dm, ln1_b + (size_t)L * Dm, Y);
        gemm64<0,0><<<dim3((3 * Dm) / 64, M / 64), 256, 0, stream>>>(
            Y, Wqkv + (size_t)L * Dm * 3 * Dm, bqkv + (size_t)L * 3 * Dm, QKV, M, 3 * Dm, Dm);
        rope_kernel<<<MROWS, 256, 0, stream>>>(QKV);
        attn_kernel<<<BATCH * NHEAD * SEQ, 256, 0, stream>>>(QKV, Y);
        gemm64<0,1><<<dim3(Dm / 64, M / 64), 256, 0, stream>>>(
            Y, Wo + (size_t)L * Dm * Dm, bo + (size_t)L * Dm, X, M, Dm, Dm);
        ln_kernel<<<MROWS, 256, 0, stream>>>(X, ln2_g + (size_t)L * Dm, ln2_b + (size_t)L * Dm, Z);
        gemm64<1,0><<<dim3(F / 64, M / 64), 256, 0, stream>>>(
            Z, W1 + (size_t)L * Dm * F, b1 + (size_t)L * F, FF, M, F, Dm);
        gemm64<0,1><<<dim3(Dm / 64, M / 64), 256, 0, stream>>>(
            FF, W2 + (size_t)L * F * Dm, b2 + (size_t)L * Dm, X, M, Dm, F);
    }

    ln_kernel<<<MROWS, 256, 0, stream>>>(X, lnf_g, lnf_b, Y);
    gemm64<0,0><<<dim3(V / 64, M / 64), 256, 0, stream>>>(Y, Wout, bout, out, M, V, Dm);
}

// Round 2
// 3179.552 us; speedup vs baseline: 5.3000x; 5.3000x over previous
//
#include <hip/hip_runtime.h>
#include <hip/hip_bf16.h>
#include <math.h>

// ---------------------------------------------------------------------------
// Round 2: bf16 MFMA GEMMs (m97 structure) + flash-tiled fp32 attention.
// B=4 S=1024 D=1024 H=8 Dh=128 F=2048 L=4 V=32000
// ---------------------------------------------------------------------------

#define D_MODEL 1024
#define SEQ     1024
#define BATCH   4
#define NHEAD   8
#define HDIM    128
#define FFN     2048
#define NLAYER  4
#define VOCAB   32000
#define MROWS   (BATCH*SEQ)   // 4096

typedef unsigned short ushort_t;
typedef __attribute__((ext_vector_type(8))) short s16x8;   // 8 bf16 = 4 VGPRs
typedef __attribute__((ext_vector_type(4))) float f32x4;

__device__ __forceinline__ ushort_t f2bf(float f) {
    union { float f; unsigned int u; } c; c.f = f;
    unsigned int u = c.u;
    unsigned int r = (u + 0x7FFFu + ((u >> 16) & 1u)) >> 16;
    return (ushort_t)r;
}

__device__ __forceinline__ void gload16(const void* g, void* l) {
    __builtin_amdgcn_global_load_lds(
        (const __attribute__((address_space(1))) unsigned int*)g,
        (__attribute__((address_space(3))) unsigned int*)l, 16, 0, 0);
}

// ---------------- embedding gather (fp32 residual stream) ----------------
__global__ __launch_bounds__(256) void embed_kernel(
    const int* __restrict__ tokens, const float* __restrict__ emb,
    float* __restrict__ X)
{
    int row = blockIdx.x;
    int t = tokens[row];
    const float4* src = (const float4*)(emb + (size_t)t * D_MODEL);
    float4* dst = (float4*)(X + (size_t)row * D_MODEL);
    dst[threadIdx.x] = src[threadIdx.x];
}

// ---------------- layernorm: fp32 in -> bf16 out ----------------
__global__ __launch_bounds__(256) void ln_kernel(
    const float* __restrict__ X, const float* __restrict__ g,
    const float* __restrict__ b, ushort_t* __restrict__ Y)
{
    __shared__ float red[8];
    int row = blockIdx.x;
    const float4* x4 = (const float4*)(X + (size_t)row * D_MODEL);
    float4 v = x4[threadIdx.x];
    float s  = v.x + v.y + v.z + v.w;
    float ss = v.x*v.x + v.y*v.y + v.z*v.z + v.w*v.w;
    #pragma unroll
    for (int o = 32; o > 0; o >>= 1) { s += __shfl_down(s, o); ss += __shfl_down(ss, o); }
    int wid = threadIdx.x >> 6;
    if ((threadIdx.x & 63) == 0) { red[wid] = s; red[wid + 4] = ss; }
    __syncthreads();
    float tot  = red[0] + red[1] + red[2] + red[3];
    float tot2 = red[4] + red[5] + red[6] + red[7];
    float mu  = tot * (1.0f / D_MODEL);
    float var = tot2 * (1.0f / D_MODEL) - mu * mu;
    float r = rsqrtf(var + 1e-5f);
    const float4* g4 = (const float4*)g;
    const float4* b4 = (const float4*)b;
    float4 gv = g4[threadIdx.x], bv = b4[threadIdx.x];
    ushort4 o;
    o.x = f2bf((v.x - mu) * r * gv.x + bv.x);
    o.y = f2bf((v.y - mu) * r * gv.y + bv.y);
    o.z = f2bf((v.z - mu) * r * gv.z + bv.z);
    o.w = f2bf((v.w - mu) * r * gv.w + bv.w);
    ((ushort4*)(Y + (size_t)row * D_MODEL))[threadIdx.x] = o;
}

// ---------------- weight fp32 [K][N] -> bf16 transposed [N][K] -------------
__global__ __launch_bounds__(256) void wconv(
    const float* __restrict__ W, ushort_t* __restrict__ Wt, int K, int N)
{
    __shared__ float t[32][33];
    const float* Wl = W + (size_t)blockIdx.z * K * N;
    ushort_t* Wtl = Wt + (size_t)blockIdx.z * K * N;
    int k0 = blockIdx.y * 32, n0 = blockIdx.x * 32;
    int tid = threadIdx.x;
    int r = tid >> 3, c4 = (tid & 7) * 4;
    float4 v = *(const float4*)(Wl + (size_t)(k0 + r) * N + n0 + c4);
    t[r][c4+0] = v.x; t[r][c4+1] = v.y; t[r][c4+2] = v.z; t[r][c4+3] = v.w;
    __syncthreads();
    ushort4 o;
    o.x = f2bf(t[c4+0][r]); o.y = f2bf(t[c4+1][r]);
    o.z = f2bf(t[c4+2][r]); o.w = f2bf(t[c4+3][r]);
    *(ushort4*)(Wtl + (size_t)(n0 + r) * K + k0 + c4) = o;
}

// ---------------- bf16 MFMA GEMM (m97 structure) ---------------------------
// C[M,N] = epi(A[M,K]bf16 @ Bt[N,K]bf16^T + bias)
// ACT: 1=exact gelu.  BETA: 1 => Cf += result (fp32).  OBF: 1 => write bf16 Cb.
__device__ __forceinline__ float gelu_exact(float x) {
    return 0.5f * x * (1.0f + erff(x * 0.70710678118654752f));
}

template<int ACT, int BETA, int OBF>
__global__ __launch_bounds__(256) void gemm_mfma(
    const ushort_t* __restrict__ A, const ushort_t* __restrict__ Bt,
    const float* __restrict__ bias, float* __restrict__ Cf,
    ushort_t* __restrict__ Cb, int M, int N, int K)
{
    __shared__ __align__(16) ushort_t As[128 * 32];   // 8 KB
    __shared__ __align__(16) ushort_t Bs[128 * 32];   // 8 KB
    int tid  = threadIdx.x;
    int lane = tid & 63, w = tid >> 6;
    int wr = w >> 1, wc = w & 1;
    int m0 = blockIdx.y * 128, n0 = blockIdx.x * 128;

    f32x4 acc[4][4] = {};

    // staging addresses: wave w stages A rows [w*32, w*32+32), same for B(t)
    const ushort_t* gA = A  + (size_t)(m0 + w * 32 + (lane >> 2)) * K + (lane & 3) * 8;
    const ushort_t* gB = Bt + (size_t)(n0 + w * 32 + (lane >> 2)) * K + (lane & 3) * 8;
    ushort_t* lA = As + w * 1024;     // wave-uniform LDS base (HW adds lane*16B)
    ushort_t* lB = Bs + w * 1024;
    const size_t gstep16 = (size_t)16 * K;

    // fragment read pointers
    int lrow = lane & 15, kg = lane >> 4;
    const s16x8* pa = (const s16x8*)(As + (wr * 64 + lrow) * 32 + kg * 8);
    const s16x8* pb = (const s16x8*)(Bs + (wc * 64 + lrow) * 32 + kg * 8);

    for (int kt = 0; kt < K / 32; ++kt) {
        gload16(gA, lA);
        gload16(gA + gstep16, lA + 512);
        gload16(gB, lB);
        gload16(gB + gstep16, lB + 512);
        gA += 32; gB += 32;
        __syncthreads();
        s16x8 a[4], b[4];
        #pragma unroll
        for (int mi = 0; mi < 4; ++mi) a[mi] = pa[mi * 64];
        #pragma unroll
        for (int ni = 0; ni < 4; ++ni) b[ni] = pb[ni * 64];
        #pragma unroll
        for (int mi = 0; mi < 4; ++mi)
            #pragma unroll
            for (int ni = 0; ni < 4; ++ni)
                acc[mi][ni] = __builtin_amdgcn_mfma_f32_16x16x32_bf16(
                    a[mi], b[ni], acc[mi][ni], 0, 0, 0);
        __syncthreads();
    }

    // epilogue: C/D layout col=lane&15, row=(lane>>4)*4+j
    #pragma unroll
    for (int mi = 0; mi < 4; ++mi) {
        int rbase = m0 + wr * 64 + mi * 16 + (lane >> 4) * 4;
        #pragma unroll
        for (int ni = 0; ni < 4; ++ni) {
            int col = n0 + wc * 64 + ni * 16 + (lane & 15);
            float bz = bias[col];
            f32x4 v = acc[mi][ni];
            #pragma unroll
            for (int j = 0; j < 4; ++j) {
                float x = v[j] + bz;
                if (ACT == 1) x = gelu_exact(x);
                size_t off = (size_t)(rbase + j) * N + col;
                if (OBF) {
                    Cb[off] = f2bf(x);
                } else {
                    if (BETA) x += Cf[off];
                    Cf[off] = x;
                }
            }
        }
    }
}

// ---------------- RoPE (in-place on fp32 QKV) ----------------
__global__ __launch_bounds__(256) void rope_kernel(float* __restrict__ QKV)
{
    int m = blockIdx.x;
    int s = m & (SEQ - 1);
    float* rowbase = QKV + (size_t)m * (3 * D_MODEL);
    #pragma unroll
    for (int r = 0; r < 4; ++r) {
        int it = threadIdx.x + r * 256;
        int qk = it >> 9;
        int rem = it & 511;
        int h = rem >> 6;
        int p = rem & 63;
        float inv = expf(-0.14391156831212788f * (float)p);
        float ang = (float)s * inv;
        float sn, c;
        sincosf(ang, &sn, &c);
        float* base = rowbase + qk * D_MODEL + h * HDIM + p;
        float x1 = base[0], x2 = base[64];
        base[0]  = x1 * c - x2 * sn;
        base[64] = x2 * c + x1 * sn;
    }
}

// ---------------- flash-tiled causal attention (fp32, bf16 out) ------------
// block = (b, h, 32-query tile); 256 threads: qr = tid>>3 (32 rows), c = tid&7
#define QT 32
#define KT 32
#define AP 132   // padded row stride (floats) for Q/K/V tiles

__global__ __launch_bounds__(256) void attn_flash(
    const float* __restrict__ QKV, ushort_t* __restrict__ Yb)
{
    __shared__ float Qs[QT][AP];
    __shared__ float Ks[KT][AP];
    __shared__ float Vs[KT][AP];
    __shared__ float Ps[QT][36];
    int bid = blockIdx.x;
    int qt = bid & 31, h = (bid >> 5) & 7, b = bid >> 8;
    int q0 = qt * QT;
    int tid = threadIdx.x;
    int qr = tid >> 3, c = tid & 7;
    const float scale = 0.08838834764831845f;   // 1/sqrt(128)

    const float* Qbase = QKV + ((size_t)(b * SEQ + q0)) * 3072 + h * HDIM;
    #pragma unroll
    for (int r4 = 0; r4 < 4; ++r4) {
        int idx = tid + r4 * 256;
        int row = idx >> 5, c4 = (idx & 31) * 4;
        *(float4*)&Qs[row][c4] = *(const float4*)(Qbase + (size_t)row * 3072 + c4);
    }

    float4 cx[4] = {};
    float mrow = -INFINITY, lrow = 0.0f;

    for (int j0 = 0; j0 < q0 + QT; j0 += KT) {
        __syncthreads();   // prior-tile LDS reads done (also covers Qs visibility)
        const float* Kb = QKV + ((size_t)(b * SEQ + j0)) * 3072 + D_MODEL + h * HDIM;
        const float* Vb = Kb + D_MODEL;
        #pragma unroll
        for (int r4 = 0; r4 < 4; ++r4) {
            int idx = tid + r4 * 256;
            int row = idx >> 5, c4 = (idx & 31) * 4;
            *(float4*)&Ks[row][c4] = *(const float4*)(Kb + (size_t)row * 3072 + c4);
            *(float4*)&Vs[row][c4] = *(const float4*)(Vb + (size_t)row * 3072 + c4);
        }
        __syncthreads();

        // scores: 4 dots per thread; kj = c + kk*8
        float sc[4];
        #pragma unroll
        for (int kk = 0; kk < 4; ++kk) {
            int kj = c + kk * 8;
            const float4* qv = (const float4*)&Qs[qr][0];
            const float4* kv = (const float4*)&Ks[kj][0];
            float d = 0.0f;
            #pragma unroll
            for (int dd = 0; dd < HDIM / 4; ++dd) {
                float4 aq = qv[dd], ak = kv[dd];
                d += aq.x*ak.x + aq.y*ak.y + aq.z*ak.z + aq.w*ak.w;
            }
            sc[kk] = (j0 + kj <= q0 + qr) ? d * scale : -INFINITY;
        }
        // online softmax over this tile's 32 keys (8 lanes x 4 regs per row)
        float tmax = fmaxf(fmaxf(sc[0], sc[1]), fmaxf(sc[2], sc[3]));
        #pragma unroll
        for (int o = 1; o < 8; o <<= 1) tmax = fmaxf(tmax, __shfl_xor(tmax, o));
        float newm = fmaxf(mrow, tmax);
        float corr = expf(mrow - newm);   // 0 on first tile
        float tsum = 0.0f;
        #pragma unroll
        for (int kk = 0; kk < 4; ++kk) {
            float p = expf(sc[kk] - newm);
            sc[kk] = p;
            tsum += p;
        }
        #pragma unroll
        for (int o = 1; o < 8; o <<= 1) tsum += __shfl_xor(tsum, o);
        lrow = lrow * corr + tsum;
        mrow = newm;
        #pragma unroll
        for (int g = 0; g < 4; ++g) cx[g] *= corr;
        #pragma unroll
        for (int kk = 0; kk < 4; ++kk) Ps[qr][c + kk * 8] = sc[kk];
        __syncthreads();

        // PV: ctx[d] += P[qr][j] * V[j][d], d = c*4 + g*32 + {0..3}
        #pragma unroll 8
        for (int j = 0; j < KT; ++j) {
            float p = Ps[qr][j];
            const float4* vr = (const float4*)&Vs[j][0];
            #pragma unroll
            for (int g = 0; g < 4; ++g) cx[g] += p * vr[c + g * 8];
        }
    }

    float inv = 1.0f / lrow;
    ushort_t* orow = Yb + (size_t)(b * SEQ + q0 + qr) * D_MODEL + h * HDIM + c * 4;
    #pragma unroll
    for (int g = 0; g < 4; ++g) {
        float4 o = cx[g];
        ushort4 u;
        u.x = f2bf(o.x * inv); u.y = f2bf(o.y * inv);
        u.z = f2bf(o.z * inv); u.w = f2bf(o.w * inv);
        *(ushort4*)(orow + g * 32) = u;
    }
}

// ---------------------------------------------------------------------------
extern "C" void kernel_launch(void* const* d_in, const int* in_sizes, int n_in,
                              void* d_out, int out_size, void* d_ws, size_t ws_size,
                              hipStream_t stream)
{
    const int*   tokens = (const int*)  d_in[0];
    const float* emb    = (const float*)d_in[1];
    const float* Wqkv   = (const float*)d_in[2];
    const float* bqkv   = (const float*)d_in[3];
    const float* Wo     = (const float*)d_in[4];
    const float* bo     = (const float*)d_in[5];
    const float* ln1_g  = (const float*)d_in[6];
    const float* ln1_b  = (const float*)d_in[7];
    const float* ln2_g  = (const float*)d_in[8];
    const float* ln2_b  = (const float*)d_in[9];
    const float* W1     = (const float*)d_in[10];
    const float* b1     = (const float*)d_in[11];
    const float* W2     = (const float*)d_in[12];
    const float* b2     = (const float*)d_in[13];
    const float* lnf_g  = (const float*)d_in[14];
    const float* lnf_b  = (const float*)d_in[15];
    const float* Wout   = (const float*)d_in[16];
    const float* bout   = (const float*)d_in[17];
    float* out = (float*)d_out;

    char* ws = (char*)d_ws;
    float*    X      = (float*)ws;                               // 16.78 MB
    float*    QKV    = (float*)(ws + 16777216);                  // 50.33 MB
    ushort_t* Abuf   = (ushort_t*)(ws + 67108864);               // 8.39 MB
    ushort_t* Gbuf   = (ushort_t*)(ws + 75497472);               // 16.78 MB
    ushort_t* WqkvT  = (ushort_t*)(ws + 92274688);               // 25.17 MB
    ushort_t* WoT    = (ushort_t*)(ws + 117440512);              // 8.39 MB
    ushort_t* W1T    = (ushort_t*)(ws + 125829120);              // 16.78 MB
    ushort_t* W2T    = (ushort_t*)(ws + 142606336);              // 16.78 MB
    ushort_t* WoutT  = (ushort_t*)(ws + 159383552);              // 65.54 MB -> 224.9 MB total

    const int M = MROWS, Dm = D_MODEL, F = FFN, V = VOCAB;

    // weight conversion (fp32 [K][N] -> bf16 [N][K]) — every call, deterministic
    wconv<<<dim3(3*Dm/32, Dm/32, NLAYER), 256, 0, stream>>>(Wqkv, WqkvT, Dm, 3*Dm);
    wconv<<<dim3(Dm/32,   Dm/32, NLAYER), 256, 0, stream>>>(Wo,   WoT,   Dm, Dm);
    wconv<<<dim3(F/32,    Dm/32, NLAYER), 256, 0, stream>>>(W1,   W1T,   Dm, F);
    wconv<<<dim3(Dm/32,   F/32,  NLAYER), 256, 0, stream>>>(W2,   W2T,   F,  Dm);
    wconv<<<dim3(V/32,    Dm/32, 1),      256, 0, stream>>>(Wout, WoutT, Dm, V);

    embed_kernel<<<MROWS, 256, 0, stream>>>(tokens, emb, X);

    for (int L = 0; L < NLAYER; ++L) {
        ln_kernel<<<MROWS, 256, 0, stream>>>(X, ln1_g + (size_t)L*Dm, ln1_b + (size_t)L*Dm, Abuf);
        gemm_mfma<0,0,0><<<dim3(3*Dm/128, M/128), 256, 0, stream>>>(
            Abuf, WqkvT + (size_t)L*3*Dm*Dm, bqkv + (size_t)L*3*Dm, QKV, nullptr, M, 3*Dm, Dm);
        rope_kernel<<<MROWS, 256, 0, stream>>>(QKV);
        attn_flash<<<BATCH*NHEAD*(SEQ/QT), 256, 0, stream>>>(QKV, Abuf);
        gemm_mfma<0,1,0><<<dim3(Dm/128, M/128), 256, 0, stream>>>(
            Abuf, WoT + (size_t)L*Dm*Dm, bo + (size_t)L*Dm, X, nullptr, M, Dm, Dm);
        ln_kernel<<<MROWS, 256, 0, stream>>>(X, ln2_g + (size_t)L*Dm, ln2_b + (size_t)L*Dm, Abuf);
        gemm_mfma<1,0,1><<<dim3(F/128, M/128), 256, 0, stream>>>(
            Abuf, W1T + (size_t)L*Dm*F, b1 + (size_t)L*F, nullptr, Gbuf, M, F, Dm);
        gemm_mfma<0,1,0><<<dim3(Dm/128, M/128), 256, 0, stream>>>(
            Gbuf, W2T + (size_t)L*F*Dm, b2 + (size_t)L*Dm, X, nullptr, M, Dm, F);
    }

    ln_kernel<<<MROWS, 256, 0, stream>>>(X, lnf_g, lnf_b, Abuf);
    gemm_mfma<0,0,0><<<dim3(V/128, M/128), 256, 0, stream>>>(
        Abuf, WoutT, bout, out, nullptr, M, V, Dm);
}

// Round 4
// 1763.574 us; speedup vs baseline: 9.5555x; 1.8029x over previous
//
#include <hip/hip_runtime.h>
#include <hip/hip_bf16.h>
#include <math.h>

// ---------------------------------------------------------------------------
// Round 4: bf16 MFMA GEMMs + bf16 MFMA flash attention.
// Fix vs round 3: Pl row stride 40 -> 72 (rows of 64 kv entries overlapped).
// B=4 S=1024 D=1024 H=8 Dh=128 F=2048 L=4 V=32000
// ---------------------------------------------------------------------------

#define D_MODEL 1024
#define SEQ     1024
#define BATCH   4
#define NHEAD   8
#define HDIM    128
#define FFN     2048
#define NLAYER  4
#define VOCAB   32000
#define MROWS   (BATCH*SEQ)   // 4096

typedef unsigned short ushort_t;
typedef __attribute__((ext_vector_type(8))) short s16x8;   // 8 bf16 = 4 VGPRs
typedef __attribute__((ext_vector_type(4))) float f32x4;

__device__ __forceinline__ ushort_t f2bf(float f) {
    union { float f; unsigned int u; } c; c.f = f;
    unsigned int u = c.u;
    unsigned int r = (u + 0x7FFFu + ((u >> 16) & 1u)) >> 16;
    return (ushort_t)r;
}

__device__ __forceinline__ void gload16(const void* g, void* l) {
    __builtin_amdgcn_global_load_lds(
        (const __attribute__((address_space(1))) unsigned int*)g,
        (__attribute__((address_space(3))) unsigned int*)l, 16, 0, 0);
}

// ---------------- embedding gather (fp32 residual stream) ----------------
__global__ __launch_bounds__(256) void embed_kernel(
    const int* __restrict__ tokens, const float* __restrict__ emb,
    float* __restrict__ X)
{
    int row = blockIdx.x;
    int t = tokens[row];
    const float4* src = (const float4*)(emb + (size_t)t * D_MODEL);
    float4* dst = (float4*)(X + (size_t)row * D_MODEL);
    dst[threadIdx.x] = src[threadIdx.x];
}

// ---------------- layernorm: fp32 in -> bf16 out ----------------
__global__ __launch_bounds__(256) void ln_kernel(
    const float* __restrict__ X, const float* __restrict__ g,
    const float* __restrict__ b, ushort_t* __restrict__ Y)
{
    __shared__ float red[8];
    int row = blockIdx.x;
    const float4* x4 = (const float4*)(X + (size_t)row * D_MODEL);
    float4 v = x4[threadIdx.x];
    float s  = v.x + v.y + v.z + v.w;
    float ss = v.x*v.x + v.y*v.y + v.z*v.z + v.w*v.w;
    #pragma unroll
    for (int o = 32; o > 0; o >>= 1) { s += __shfl_down(s, o); ss += __shfl_down(ss, o); }
    int wid = threadIdx.x >> 6;
    if ((threadIdx.x & 63) == 0) { red[wid] = s; red[wid + 4] = ss; }
    __syncthreads();
    float tot  = red[0] + red[1] + red[2] + red[3];
    float tot2 = red[4] + red[5] + red[6] + red[7];
    float mu  = tot * (1.0f / D_MODEL);
    float var = tot2 * (1.0f / D_MODEL) - mu * mu;
    float r = rsqrtf(var + 1e-5f);
    const float4* g4 = (const float4*)g;
    const float4* b4 = (const float4*)b;
    float4 gv = g4[threadIdx.x], bv = b4[threadIdx.x];
    ushort4 o;
    o.x = f2bf((v.x - mu) * r * gv.x + bv.x);
    o.y = f2bf((v.y - mu) * r * gv.y + bv.y);
    o.z = f2bf((v.z - mu) * r * gv.z + bv.z);
    o.w = f2bf((v.w - mu) * r * gv.w + bv.w);
    ((ushort4*)(Y + (size_t)row * D_MODEL))[threadIdx.x] = o;
}

// ---------------- weight fp32 [K][N] -> bf16 transposed [N][K] -------------
__global__ __launch_bounds__(256) void wconv(
    const float* __restrict__ W, ushort_t* __restrict__ Wt, int K, int N)
{
    __shared__ float t[32][33];
    const float* Wl = W + (size_t)blockIdx.z * K * N;
    ushort_t* Wtl = Wt + (size_t)blockIdx.z * K * N;
    int k0 = blockIdx.y * 32, n0 = blockIdx.x * 32;
    int tid = threadIdx.x;
    int r = tid >> 3, c4 = (tid & 7) * 4;
    float4 v = *(const float4*)(Wl + (size_t)(k0 + r) * N + n0 + c4);
    t[r][c4+0] = v.x; t[r][c4+1] = v.y; t[r][c4+2] = v.z; t[r][c4+3] = v.w;
    __syncthreads();
    ushort4 o;
    o.x = f2bf(t[c4+0][r]); o.y = f2bf(t[c4+1][r]);
    o.z = f2bf(t[c4+2][r]); o.w = f2bf(t[c4+3][r]);
    *(ushort4*)(Wtl + (size_t)(n0 + r) * K + k0 + c4) = o;
}

// ---------------- bf16 MFMA GEMM (m97 structure) ---------------------------
__device__ __forceinline__ float gelu_exact(float x) {
    return 0.5f * x * (1.0f + erff(x * 0.70710678118654752f));
}

template<int ACT, int BETA, int OBF>
__global__ __launch_bounds__(256) void gemm_mfma(
    const ushort_t* __restrict__ A, const ushort_t* __restrict__ Bt,
    const float* __restrict__ bias, float* __restrict__ Cf,
    ushort_t* __restrict__ Cb, int M, int N, int K)
{
    __shared__ __align__(16) ushort_t As[128 * 32];
    __shared__ __align__(16) ushort_t Bs[128 * 32];
    int tid  = threadIdx.x;
    int lane = tid & 63, w = tid >> 6;
    int wr = w >> 1, wc = w & 1;
    int m0 = blockIdx.y * 128, n0 = blockIdx.x * 128;

    f32x4 acc[4][4] = {};

    const ushort_t* gA = A  + (size_t)(m0 + w * 32 + (lane >> 2)) * K + (lane & 3) * 8;
    const ushort_t* gB = Bt + (size_t)(n0 + w * 32 + (lane >> 2)) * K + (lane & 3) * 8;
    ushort_t* lA = As + w * 1024;
    ushort_t* lB = Bs + w * 1024;
    const size_t gstep16 = (size_t)16 * K;

    int lrow = lane & 15, kg = lane >> 4;
    const s16x8* pa = (const s16x8*)(As + (wr * 64 + lrow) * 32 + kg * 8);
    const s16x8* pb = (const s16x8*)(Bs + (wc * 64 + lrow) * 32 + kg * 8);

    for (int kt = 0; kt < K / 32; ++kt) {
        gload16(gA, lA);
        gload16(gA + gstep16, lA + 512);
        gload16(gB, lB);
        gload16(gB + gstep16, lB + 512);
        gA += 32; gB += 32;
        __syncthreads();
        s16x8 a[4], b[4];
        #pragma unroll
        for (int mi = 0; mi < 4; ++mi) a[mi] = pa[mi * 64];
        #pragma unroll
        for (int ni = 0; ni < 4; ++ni) b[ni] = pb[ni * 64];
        #pragma unroll
        for (int mi = 0; mi < 4; ++mi)
            #pragma unroll
            for (int ni = 0; ni < 4; ++ni)
                acc[mi][ni] = __builtin_amdgcn_mfma_f32_16x16x32_bf16(
                    a[mi], b[ni], acc[mi][ni], 0, 0, 0);
        __syncthreads();
    }

    #pragma unroll
    for (int mi = 0; mi < 4; ++mi) {
        int rbase = m0 + wr * 64 + mi * 16 + (lane >> 4) * 4;
        #pragma unroll
        for (int ni = 0; ni < 4; ++ni) {
            int col = n0 + wc * 64 + ni * 16 + (lane & 15);
            float bz = bias[col];
            f32x4 v = acc[mi][ni];
            #pragma unroll
            for (int j = 0; j < 4; ++j) {
                float x = v[j] + bz;
                if (ACT == 1) x = gelu_exact(x);
                size_t off = (size_t)(rbase + j) * N + col;
                if (OBF) {
                    Cb[off] = f2bf(x);
                } else {
                    if (BETA) x += Cf[off];
                    Cf[off] = x;
                }
            }
        }
    }
}

// ---------------- RoPE + bf16: QKV fp32 -> Qb, Kb [B,H,S,Dh] ---------------
__global__ __launch_bounds__(256) void ropeq_kernel(
    const float* __restrict__ QKV, ushort_t* __restrict__ Qb,
    ushort_t* __restrict__ Kb)
{
    int m = blockIdx.x;
    int b = m >> 10, s = m & (SEQ - 1);
    const float* rowbase = QKV + (size_t)m * (3 * D_MODEL);
    #pragma unroll
    for (int r = 0; r < 4; ++r) {
        int it = threadIdx.x + r * 256;   // 0..1023
        int qk = it >> 9;                 // 0=Q 1=K
        int rem = it & 511;
        int hh = rem >> 6;
        int p = rem & 63;
        float inv = expf(-0.14391156831212788f * (float)p);
        float ang = (float)s * inv;
        float sn, c;
        sincosf(ang, &sn, &c);
        const float* base = rowbase + qk * D_MODEL + hh * HDIM + p;
        float x1 = base[0], x2 = base[64];
        ushort_t* dst = (qk ? Kb : Qb) + ((size_t)(b * NHEAD + hh) * SEQ + s) * HDIM + p;
        dst[0]  = f2bf(x1 * c - x2 * sn);
        dst[64] = f2bf(x2 * c + x1 * sn);
    }
}

// ---------------- V transpose: QKV fp32 V-part -> bf16 Vt [B,1024,S] -------
__global__ __launch_bounds__(256) void vtrans_kernel(
    const float* __restrict__ QKV, ushort_t* __restrict__ Vt)
{
    __shared__ float tl[64][33];
    int s0 = blockIdx.x * 64;
    int d0 = blockIdx.y * 32;
    int b  = blockIdx.z;
    int tid = threadIdx.x;
    #pragma unroll
    for (int r = 0; r < 8; ++r) {
        int li = tid + r * 256;
        int row = li >> 5, col = li & 31;
        tl[row][col] = QKV[(size_t)(b * SEQ + s0 + row) * 3072 + 2 * D_MODEL + d0 + col];
    }
    __syncthreads();
    #pragma unroll
    for (int r = 0; r < 8; ++r) {
        int li = tid + r * 256;
        int drow = li >> 6, scol = li & 63;
        Vt[(size_t)(b * D_MODEL + d0 + drow) * SEQ + s0 + scol] = f2bf(tl[scol][drow]);
    }
}

// ---------------- MFMA flash attention -------------------------------------
// block = (b, h, 64-row q-tile); 4 waves, wave w owns q rows [w*16, w*16+16)
#define PSTR 72   // P row stride (>=64, padded for bank spread)

__global__ __launch_bounds__(256) void attn_mfma(
    const ushort_t* __restrict__ Qb, const ushort_t* __restrict__ Kb,
    const ushort_t* __restrict__ Vt, ushort_t* __restrict__ Yb)
{
    __shared__ __align__(16) ushort_t Ks[64 * 136];     // pad 136: 2-way banks
    __shared__ __align__(16) ushort_t Vts[128 * 72];    // pad 72:  2-way banks
    __shared__ __align__(16) ushort_t Pl[4][16 * PSTR]; // 16 q rows x 64 kv
    int bid = blockIdx.x;
    int qt = bid & 15, h = (bid >> 4) & 7, b = bid >> 7;
    int q0 = qt * 64;
    int tid = threadIdx.x, lane = tid & 63, w = tid >> 6;
    int lr = lane & 15, g = lane >> 4;
    const float scale = 0.08838834764831845f;   // 1/sqrt(128)

    const ushort_t* Qbase = Qb + (size_t)((b * NHEAD + h) * SEQ) * HDIM;
    const ushort_t* Kbase = Kb + (size_t)((b * NHEAD + h) * SEQ) * HDIM;
    const ushort_t* Vbase = Vt + (size_t)(b * D_MODEL + h * HDIM) * SEQ;

    // Q fragments for this wave's 16 rows, all of Dh=128 (4 k-chunks)
    s16x8 aq[4];
    #pragma unroll
    for (int kc = 0; kc < 4; ++kc)
        aq[kc] = *(const s16x8*)(Qbase + (size_t)(q0 + w * 16 + lr) * HDIM + kc * 32 + g * 8);

    f32x4 acc_o[8] = {};
    float mx[4] = {-INFINITY, -INFINITY, -INFINITY, -INFINITY};
    float ls[4] = {};

    int ntiles = q0 / 64 + 1;
    for (int t = 0; t < ntiles; ++t) {
        int j0 = t * 64;
        __syncthreads();
        // stage K tile [64 kv][128 dh]
        #pragma unroll
        for (int r = 0; r < 4; ++r) {
            int idx = tid + r * 256;
            int row = idx >> 4, c16 = idx & 15;
            *(s16x8*)&Ks[row * 136 + c16 * 8] =
                *(const s16x8*)(Kbase + (size_t)(j0 + row) * HDIM + c16 * 8);
        }
        // stage V^T tile [128 d][64 kv]
        #pragma unroll
        for (int r = 0; r < 4; ++r) {
            int idx = tid + r * 256;
            int row = idx >> 3, c8 = idx & 7;
            *(s16x8*)&Vts[row * 72 + c8 * 8] =
                *(const s16x8*)(Vbase + (size_t)row * SEQ + j0 + c8 * 8);
        }
        __syncthreads();

        // QK^T: S[16 q x 64 kv] per wave
        f32x4 sa[4] = {};
        #pragma unroll
        for (int nb = 0; nb < 4; ++nb)
            #pragma unroll
            for (int kc = 0; kc < 4; ++kc) {
                s16x8 bk = *(const s16x8*)&Ks[(nb * 16 + lr) * 136 + kc * 32 + g * 8];
                sa[nb] = __builtin_amdgcn_mfma_f32_16x16x32_bf16(aq[kc], bk, sa[nb], 0, 0, 0);
            }

        bool diag = (j0 == q0);
        float pv[4][4];
        #pragma unroll
        for (int nb = 0; nb < 4; ++nb)
            #pragma unroll
            for (int j = 0; j < 4; ++j) {
                float v = sa[nb][j] * scale;
                if (diag) {
                    int kv = j0 + nb * 16 + lr;
                    int qq = q0 + w * 16 + g * 4 + j;
                    if (kv > qq) v = -INFINITY;
                }
                pv[nb][j] = v;
            }
        // online softmax per q row (row = g*4+j, lane-local across dn)
        #pragma unroll
        for (int j = 0; j < 4; ++j) {
            float tm = fmaxf(fmaxf(pv[0][j], pv[1][j]), fmaxf(pv[2][j], pv[3][j]));
            #pragma unroll
            for (int o = 1; o < 16; o <<= 1) tm = fmaxf(tm, __shfl_xor(tm, o));
            float nm = fmaxf(mx[j], tm);
            float corr = expf(mx[j] - nm);
            float ts = 0.0f;
            #pragma unroll
            for (int nb = 0; nb < 4; ++nb) {
                float e = expf(pv[nb][j] - nm);
                pv[nb][j] = e;
                ts += e;
            }
            #pragma unroll
            for (int o = 1; o < 16; o <<= 1) ts += __shfl_xor(ts, o);
            ls[j] = ls[j] * corr + ts;
            mx[j] = nm;
            #pragma unroll
            for (int dn = 0; dn < 8; ++dn) acc_o[dn][j] *= corr;
        }
        // P (bf16) -> wave-private LDS [16 q][64 kv], stride PSTR
        #pragma unroll
        for (int nb = 0; nb < 4; ++nb)
            #pragma unroll
            for (int j = 0; j < 4; ++j)
                Pl[w][(g * 4 + j) * PSTR + nb * 16 + lr] = f2bf(pv[nb][j]);
        // PV: O[16 q x 128 d] += P @ V
        #pragma unroll
        for (int kk = 0; kk < 2; ++kk) {
            s16x8 pa = *(const s16x8*)&Pl[w][lr * PSTR + kk * 32 + g * 8];
            #pragma unroll
            for (int dn = 0; dn < 8; ++dn) {
                s16x8 bv = *(const s16x8*)&Vts[(dn * 16 + lr) * 72 + kk * 32 + g * 8];
                acc_o[dn] = __builtin_amdgcn_mfma_f32_16x16x32_bf16(pa, bv, acc_o[dn], 0, 0, 0);
            }
        }
    }

    float il[4];
    #pragma unroll
    for (int j = 0; j < 4; ++j) il[j] = 1.0f / ls[j];
    #pragma unroll
    for (int dn = 0; dn < 8; ++dn)
        #pragma unroll
        for (int j = 0; j < 4; ++j) {
            int q = q0 + w * 16 + g * 4 + j;
            Yb[(size_t)(b * SEQ + q) * D_MODEL + h * HDIM + dn * 16 + lr] =
                f2bf(acc_o[dn][j] * il[j]);
        }
}

// ---------------------------------------------------------------------------
extern "C" void kernel_launch(void* const* d_in, const int* in_sizes, int n_in,
                              void* d_out, int out_size, void* d_ws, size_t ws_size,
                              hipStream_t stream)
{
    const int*   tokens = (const int*)  d_in[0];
    const float* emb    = (const float*)d_in[1];
    const float* Wqkv   = (const float*)d_in[2];
    const float* bqkv   = (const float*)d_in[3];
    const float* Wo     = (const float*)d_in[4];
    const float* bo     = (const float*)d_in[5];
    const float* ln1_g  = (const float*)d_in[6];
    const float* ln1_b  = (const float*)d_in[7];
    const float* ln2_g  = (const float*)d_in[8];
    const float* ln2_b  = (const float*)d_in[9];
    const float* W1     = (const float*)d_in[10];
    const float* b1     = (const float*)d_in[11];
    const float* W2     = (const float*)d_in[12];
    const float* b2     = (const float*)d_in[13];
    const float* lnf_g  = (const float*)d_in[14];
    const float* lnf_b  = (const float*)d_in[15];
    const float* Wout   = (const float*)d_in[16];
    const float* bout   = (const float*)d_in[17];
    float* out = (float*)d_out;

    char* ws = (char*)d_ws;
    float*    X      = (float*)ws;                     // 16.78 MB
    float*    QKV    = (float*)(ws + 16777216);        // 50.33 MB
    ushort_t* Abuf   = (ushort_t*)(ws + 67108864);     // 8.39 MB
    ushort_t* Gbuf   = (ushort_t*)(ws + 75497472);     // 16.78 MB (FFN phase)
    ushort_t* Qbb    = (ushort_t*)(ws + 75497472);     //   alias: attn phase Q
    ushort_t* Kbb    = (ushort_t*)(ws + 83886080);     //   alias: attn phase K
    ushort_t* Vtb    = (ushort_t*)(ws + 92274688);     // 8.39 MB
    ushort_t* WqkvT  = (ushort_t*)(ws + 100663296);    // 25.17 MB
    ushort_t* WoT    = (ushort_t*)(ws + 125829120);    // 8.39 MB
    ushort_t* W1T    = (ushort_t*)(ws + 134217728);    // 16.78 MB
    ushort_t* W2T    = (ushort_t*)(ws + 150994944);    // 16.78 MB
    ushort_t* WoutT  = (ushort_t*)(ws + 167772160);    // 65.54 MB -> 233.3 MB total

    const int M = MROWS, Dm = D_MODEL, F = FFN, V = VOCAB;

    wconv<<<dim3(3*Dm/32, Dm/32, NLAYER), 256, 0, stream>>>(Wqkv, WqkvT, Dm, 3*Dm);
    wconv<<<dim3(Dm/32,   Dm/32, NLAYER), 256, 0, stream>>>(Wo,   WoT,   Dm, Dm);
    wconv<<<dim3(F/32,    Dm/32, NLAYER), 256, 0, stream>>>(W1,   W1T,   Dm, F);
    wconv<<<dim3(Dm/32,   F/32,  NLAYER), 256, 0, stream>>>(W2,   W2T,   F,  Dm);
    wconv<<<dim3(V/32,    Dm/32, 1),      256, 0, stream>>>(Wout, WoutT, Dm, V);

    embed_kernel<<<MROWS, 256, 0, stream>>>(tokens, emb, X);

    for (int L = 0; L < NLAYER; ++L) {
        ln_kernel<<<MROWS, 256, 0, stream>>>(X, ln1_g + (size_t)L*Dm, ln1_b + (size_t)L*Dm, Abuf);
        gemm_mfma<0,0,0><<<dim3(3*Dm/128, M/128), 256, 0, stream>>>(
            Abuf, WqkvT + (size_t)L*3*Dm*Dm, bqkv + (size_t)L*3*Dm, QKV, nullptr, M, 3*Dm, Dm);
        ropeq_kernel<<<MROWS, 256, 0, stream>>>(QKV, Qbb, Kbb);
        vtrans_kernel<<<dim3(SEQ/64, Dm/32, BATCH), 256, 0, stream>>>(QKV, Vtb);
        attn_mfma<<<BATCH*NHEAD*(SEQ/64), 256, 0, stream>>>(Qbb, Kbb, Vtb, Abuf);
        gemm_mfma<0,1,0><<<dim3(Dm/128, M/128), 256, 0, stream>>>(
            Abuf, WoT + (size_t)L*Dm*Dm, bo + (size_t)L*Dm, X, nullptr, M, Dm, Dm);
        ln_kernel<<<MROWS, 256, 0, stream>>>(X, ln2_g + (size_t)L*Dm, ln2_b + (size_t)L*Dm, Abuf);
        gemm_mfma<1,0,1><<<dim3(F/128, M/128), 256, 0, stream>>>(
            Abuf, W1T + (size_t)L*Dm*F, b1 + (size_t)L*F, nullptr, Gbuf, M, F, Dm);
        gemm_mfma<0,1,0><<<dim3(Dm/128, M/128), 256, 0, stream>>>(
            Gbuf, W2T + (size_t)L*F*Dm, b2 + (size_t)L*Dm, X, nullptr, M, Dm, F);
    }

    ln_kernel<<<MROWS, 256, 0, stream>>>(X, lnf_g, lnf_b, Abuf);
    gemm_mfma<0,0,0><<<dim3(V/128, M/128), 256, 0, stream>>>(
        Abuf, WoutT, bout, out, nullptr, M, V, Dm);
}

// Round 5
// 1697.976 us; speedup vs baseline: 9.9246x; 1.0386x over previous
//
#include <hip/hip_runtime.h>
#include <hip/hip_bf16.h>
#include <math.h>

// ---------------------------------------------------------------------------
// Round 5: grid remap (x=M-panel) for B-operand L2/L3 reuse + bf16 QKV path.
// B=4 S=1024 D=1024 H=8 Dh=128 F=2048 L=4 V=32000
// ---------------------------------------------------------------------------

#define D_MODEL 1024
#define SEQ     1024
#define BATCH   4
#define NHEAD   8
#define HDIM    128
#define FFN     2048
#define NLAYER  4
#define VOCAB   32000
#define MROWS   (BATCH*SEQ)   // 4096

typedef unsigned short ushort_t;
typedef __attribute__((ext_vector_type(8))) short s16x8;   // 8 bf16 = 4 VGPRs
typedef __attribute__((ext_vector_type(4))) float f32x4;

__device__ __forceinline__ ushort_t f2bf(float f) {
    union { float f; unsigned int u; } c; c.f = f;
    unsigned int u = c.u;
    unsigned int r = (u + 0x7FFFu + ((u >> 16) & 1u)) >> 16;
    return (ushort_t)r;
}
__device__ __forceinline__ float bf2f(ushort_t u) {
    union { unsigned int u; float f; } c; c.u = ((unsigned int)u) << 16; return c.f;
}

__device__ __forceinline__ void gload16(const void* g, void* l) {
    __builtin_amdgcn_global_load_lds(
        (const __attribute__((address_space(1))) unsigned int*)g,
        (__attribute__((address_space(3))) unsigned int*)l, 16, 0, 0);
}

// ---------------- embedding gather (fp32 residual stream) ----------------
__global__ __launch_bounds__(256) void embed_kernel(
    const int* __restrict__ tokens, const float* __restrict__ emb,
    float* __restrict__ X)
{
    int row = blockIdx.x;
    int t = tokens[row];
    const float4* src = (const float4*)(emb + (size_t)t * D_MODEL);
    float4* dst = (float4*)(X + (size_t)row * D_MODEL);
    dst[threadIdx.x] = src[threadIdx.x];
}

// ---------------- layernorm: fp32 in -> bf16 out ----------------
__global__ __launch_bounds__(256) void ln_kernel(
    const float* __restrict__ X, const float* __restrict__ g,
    const float* __restrict__ b, ushort_t* __restrict__ Y)
{
    __shared__ float red[8];
    int row = blockIdx.x;
    const float4* x4 = (const float4*)(X + (size_t)row * D_MODEL);
    float4 v = x4[threadIdx.x];
    float s  = v.x + v.y + v.z + v.w;
    float ss = v.x*v.x + v.y*v.y + v.z*v.z + v.w*v.w;
    #pragma unroll
    for (int o = 32; o > 0; o >>= 1) { s += __shfl_down(s, o); ss += __shfl_down(ss, o); }
    int wid = threadIdx.x >> 6;
    if ((threadIdx.x & 63) == 0) { red[wid] = s; red[wid + 4] = ss; }
    __syncthreads();
    float tot  = red[0] + red[1] + red[2] + red[3];
    float tot2 = red[4] + red[5] + red[6] + red[7];
    float mu  = tot * (1.0f / D_MODEL);
    float var = tot2 * (1.0f / D_MODEL) - mu * mu;
    float r = rsqrtf(var + 1e-5f);
    const float4* g4 = (const float4*)g;
    const float4* b4 = (const float4*)b;
    float4 gv = g4[threadIdx.x], bv = b4[threadIdx.x];
    ushort4 o;
    o.x = f2bf((v.x - mu) * r * gv.x + bv.x);
    o.y = f2bf((v.y - mu) * r * gv.y + bv.y);
    o.z = f2bf((v.z - mu) * r * gv.z + bv.z);
    o.w = f2bf((v.w - mu) * r * gv.w + bv.w);
    ((ushort4*)(Y + (size_t)row * D_MODEL))[threadIdx.x] = o;
}

// ---------------- weight fp32 [K][N] -> bf16 transposed [N][K] -------------
__global__ __launch_bounds__(256) void wconv(
    const float* __restrict__ W, ushort_t* __restrict__ Wt, int K, int N)
{
    __shared__ float t[32][33];
    const float* Wl = W + (size_t)blockIdx.z * K * N;
    ushort_t* Wtl = Wt + (size_t)blockIdx.z * K * N;
    int k0 = blockIdx.y * 32, n0 = blockIdx.x * 32;
    int tid = threadIdx.x;
    int r = tid >> 3, c4 = (tid & 7) * 4;
    float4 v = *(const float4*)(Wl + (size_t)(k0 + r) * N + n0 + c4);
    t[r][c4+0] = v.x; t[r][c4+1] = v.y; t[r][c4+2] = v.z; t[r][c4+3] = v.w;
    __syncthreads();
    ushort4 o;
    o.x = f2bf(t[c4+0][r]); o.y = f2bf(t[c4+1][r]);
    o.z = f2bf(t[c4+2][r]); o.w = f2bf(t[c4+3][r]);
    *(ushort4*)(Wtl + (size_t)(n0 + r) * K + k0 + c4) = o;
}

// ---------------- bf16 MFMA GEMM (m97 structure) ---------------------------
// grid: x = M-panel (fast), y = N-panel  => XCD = m%8, A L2-resident, B ~1x HBM
__device__ __forceinline__ float gelu_exact(float x) {
    return 0.5f * x * (1.0f + erff(x * 0.70710678118654752f));
}

template<int ACT, int BETA, int OBF>
__global__ __launch_bounds__(256) void gemm_mfma(
    const ushort_t* __restrict__ A, const ushort_t* __restrict__ Bt,
    const float* __restrict__ bias, float* __restrict__ Cf,
    ushort_t* __restrict__ Cb, int M, int N, int K)
{
    __shared__ __align__(16) ushort_t As[128 * 32];
    __shared__ __align__(16) ushort_t Bs[128 * 32];
    int tid  = threadIdx.x;
    int lane = tid & 63, w = tid >> 6;
    int wr = w >> 1, wc = w & 1;
    int m0 = blockIdx.x * 128, n0 = blockIdx.y * 128;

    f32x4 acc[4][4] = {};

    const ushort_t* gA = A  + (size_t)(m0 + w * 32 + (lane >> 2)) * K + (lane & 3) * 8;
    const ushort_t* gB = Bt + (size_t)(n0 + w * 32 + (lane >> 2)) * K + (lane & 3) * 8;
    ushort_t* lA = As + w * 1024;
    ushort_t* lB = Bs + w * 1024;
    const size_t gstep16 = (size_t)16 * K;

    int lrow = lane & 15, kg = lane >> 4;
    const s16x8* pa = (const s16x8*)(As + (wr * 64 + lrow) * 32 + kg * 8);
    const s16x8* pb = (const s16x8*)(Bs + (wc * 64 + lrow) * 32 + kg * 8);

    for (int kt = 0; kt < K / 32; ++kt) {
        gload16(gA, lA);
        gload16(gA + gstep16, lA + 512);
        gload16(gB, lB);
        gload16(gB + gstep16, lB + 512);
        gA += 32; gB += 32;
        __syncthreads();
        s16x8 a[4], b[4];
        #pragma unroll
        for (int mi = 0; mi < 4; ++mi) a[mi] = pa[mi * 64];
        #pragma unroll
        for (int ni = 0; ni < 4; ++ni) b[ni] = pb[ni * 64];
        #pragma unroll
        for (int mi = 0; mi < 4; ++mi)
            #pragma unroll
            for (int ni = 0; ni < 4; ++ni)
                acc[mi][ni] = __builtin_amdgcn_mfma_f32_16x16x32_bf16(
                    a[mi], b[ni], acc[mi][ni], 0, 0, 0);
        __syncthreads();
    }

    #pragma unroll
    for (int mi = 0; mi < 4; ++mi) {
        int rbase = m0 + wr * 64 + mi * 16 + (lane >> 4) * 4;
        #pragma unroll
        for (int ni = 0; ni < 4; ++ni) {
            int col = n0 + wc * 64 + ni * 16 + (lane & 15);
            float bz = bias[col];
            f32x4 v = acc[mi][ni];
            #pragma unroll
            for (int j = 0; j < 4; ++j) {
                float x = v[j] + bz;
                if (ACT == 1) x = gelu_exact(x);
                size_t off = (size_t)(rbase + j) * N + col;
                if (OBF) {
                    Cb[off] = f2bf(x);
                } else {
                    if (BETA) x += Cf[off];
                    Cf[off] = x;
                }
            }
        }
    }
}

// ---------------- RoPE: bf16 QKV -> bf16 Qb, Kb [B,H,S,Dh] ---------------
__global__ __launch_bounds__(256) void ropeq_kernel(
    const ushort_t* __restrict__ QKVb, ushort_t* __restrict__ Qb,
    ushort_t* __restrict__ Kb)
{
    int m = blockIdx.x;
    int b = m >> 10, s = m & (SEQ - 1);
    const ushort_t* rowbase = QKVb + (size_t)m * (3 * D_MODEL);
    #pragma unroll
    for (int r = 0; r < 4; ++r) {
        int it = threadIdx.x + r * 256;   // 0..1023
        int qk = it >> 9;                 // 0=Q 1=K
        int rem = it & 511;
        int hh = rem >> 6;
        int p = rem & 63;
        float inv = expf(-0.14391156831212788f * (float)p);
        float ang = (float)s * inv;
        float sn, c;
        sincosf(ang, &sn, &c);
        const ushort_t* base = rowbase + qk * D_MODEL + hh * HDIM + p;
        float x1 = bf2f(base[0]), x2 = bf2f(base[64]);
        ushort_t* dst = (qk ? Kb : Qb) + ((size_t)(b * NHEAD + hh) * SEQ + s) * HDIM + p;
        dst[0]  = f2bf(x1 * c - x2 * sn);
        dst[64] = f2bf(x2 * c + x1 * sn);
    }
}

// ---------------- V transpose: bf16 QKV V-part -> bf16 Vt [B,1024,S] -------
__global__ __launch_bounds__(256) void vtrans_kernel(
    const ushort_t* __restrict__ QKVb, ushort_t* __restrict__ Vt)
{
    __shared__ ushort_t tl[64][34];   // stride 68B = 17 banks -> conflict-free
    int s0 = blockIdx.x * 64;
    int d0 = blockIdx.y * 32;
    int b  = blockIdx.z;
    int tid = threadIdx.x;
    // load 64 s-rows x 32 d-cols (ushort2 per thread per iter)
    #pragma unroll
    for (int r = 0; r < 2; ++r) {
        int li = tid + r * 256;            // 0..511
        int row = li >> 4;                 // 0..31 then 32..63... need 64 rows
        int cp  = (li & 15) * 2;
        // two rows per li pass: rows 0..31 (r=0), 32..63 (r=1)
        const ushort_t* src = QKVb + (size_t)(b * SEQ + s0 + row + r * 0) * 3072
                              + 2 * D_MODEL + d0 + cp;
        // NOTE: row covers 0..31 for r=0 via li>>4; for r=1 li in 256..511 -> row 16..31?
        (void)src;
    }
    // simpler correct form: 64 rows x 32 cols = 2048 ushorts = 1024 ushort2;
    // 256 threads x 4 iters
    #pragma unroll
    for (int r = 0; r < 4; ++r) {
        int li = tid + r * 256;            // 0..1023
        int row = li >> 4;                 // 0..63
        int cp  = (li & 15) * 2;           // 0..30
        ushort2 v = *(const ushort2*)(QKVb + (size_t)(b * SEQ + s0 + row) * 3072
                                      + 2 * D_MODEL + d0 + cp);
        tl[row][cp]     = v.x;
        tl[row][cp + 1] = v.y;
    }
    __syncthreads();
    // store 32 d-rows x 64 s-cols (ushort2 along s)
    #pragma unroll
    for (int r = 0; r < 4; ++r) {
        int li = tid + r * 256;            // 0..1023
        int drow = li >> 5;                // 0..31
        int sc   = (li & 31) * 2;          // 0..62
        ushort2 o;
        o.x = tl[sc][drow];
        o.y = tl[sc + 1][drow];
        *(ushort2*)(Vt + (size_t)(b * D_MODEL + d0 + drow) * SEQ + s0 + sc) = o;
    }
}

// ---------------- MFMA flash attention -------------------------------------
// block = (b, h, 64-row q-tile); 4 waves, wave w owns q rows [w*16, w*16+16)
#define PSTR 72   // P row stride (>=64, padded for bank spread)

__global__ __launch_bounds__(256) void attn_mfma(
    const ushort_t* __restrict__ Qb, const ushort_t* __restrict__ Kb,
    const ushort_t* __restrict__ Vt, ushort_t* __restrict__ Yb)
{
    __shared__ __align__(16) ushort_t Ks[64 * 136];     // pad 136: 2-way banks
    __shared__ __align__(16) ushort_t Vts[128 * 72];    // pad 72:  2-way banks
    __shared__ __align__(16) ushort_t Pl[4][16 * PSTR]; // 16 q rows x 64 kv
    int bid = blockIdx.x;
    int qt = bid & 15, h = (bid >> 4) & 7, b = bid >> 7;
    int q0 = qt * 64;
    int tid = threadIdx.x, lane = tid & 63, w = tid >> 6;
    int lr = lane & 15, g = lane >> 4;
    const float scale = 0.08838834764831845f;   // 1/sqrt(128)

    const ushort_t* Qbase = Qb + (size_t)((b * NHEAD + h) * SEQ) * HDIM;
    const ushort_t* Kbase = Kb + (size_t)((b * NHEAD + h) * SEQ) * HDIM;
    const ushort_t* Vbase = Vt + (size_t)(b * D_MODEL + h * HDIM) * SEQ;

    s16x8 aq[4];
    #pragma unroll
    for (int kc = 0; kc < 4; ++kc)
        aq[kc] = *(const s16x8*)(Qbase + (size_t)(q0 + w * 16 + lr) * HDIM + kc * 32 + g * 8);

    f32x4 acc_o[8] = {};
    float mx[4] = {-INFINITY, -INFINITY, -INFINITY, -INFINITY};
    float ls[4] = {};

    int ntiles = q0 / 64 + 1;
    for (int t = 0; t < ntiles; ++t) {
        int j0 = t * 64;
        __syncthreads();
        #pragma unroll
        for (int r = 0; r < 4; ++r) {
            int idx = tid + r * 256;
            int row = idx >> 4, c16 = idx & 15;
            *(s16x8*)&Ks[row * 136 + c16 * 8] =
                *(const s16x8*)(Kbase + (size_t)(j0 + row) * HDIM + c16 * 8);
        }
        #pragma unroll
        for (int r = 0; r < 4; ++r) {
            int idx = tid + r * 256;
            int row = idx >> 3, c8 = idx & 7;
            *(s16x8*)&Vts[row * 72 + c8 * 8] =
                *(const s16x8*)(Vbase + (size_t)row * SEQ + j0 + c8 * 8);
        }
        __syncthreads();

        f32x4 sa[4] = {};
        #pragma unroll
        for (int nb = 0; nb < 4; ++nb)
            #pragma unroll
            for (int kc = 0; kc < 4; ++kc) {
                s16x8 bk = *(const s16x8*)&Ks[(nb * 16 + lr) * 136 + kc * 32 + g * 8];
                sa[nb] = __builtin_amdgcn_mfma_f32_16x16x32_bf16(aq[kc], bk, sa[nb], 0, 0, 0);
            }

        bool diag = (j0 == q0);
        float pv[4][4];
        #pragma unroll
        for (int nb = 0; nb < 4; ++nb)
            #pragma unroll
            for (int j = 0; j < 4; ++j) {
                float v = sa[nb][j] * scale;
                if (diag) {
                    int kv = j0 + nb * 16 + lr;
                    int qq = q0 + w * 16 + g * 4 + j;
                    if (kv > qq) v = -INFINITY;
                }
                pv[nb][j] = v;
            }
        #pragma unroll
        for (int j = 0; j < 4; ++j) {
            float tm = fmaxf(fmaxf(pv[0][j], pv[1][j]), fmaxf(pv[2][j], pv[3][j]));
            #pragma unroll
            for (int o = 1; o < 16; o <<= 1) tm = fmaxf(tm, __shfl_xor(tm, o));
            float nm = fmaxf(mx[j], tm);
            float corr = expf(mx[j] - nm);
            float ts = 0.0f;
            #pragma unroll
            for (int nb = 0; nb < 4; ++nb) {
                float e = expf(pv[nb][j] - nm);
                pv[nb][j] = e;
                ts += e;
            }
            #pragma unroll
            for (int o = 1; o < 16; o <<= 1) ts += __shfl_xor(ts, o);
            ls[j] = ls[j] * corr + ts;
            mx[j] = nm;
            #pragma unroll
            for (int dn = 0; dn < 8; ++dn) acc_o[dn][j] *= corr;
        }
        #pragma unroll
        for (int nb = 0; nb < 4; ++nb)
            #pragma unroll
            for (int j = 0; j < 4; ++j)
                Pl[w][(g * 4 + j) * PSTR + nb * 16 + lr] = f2bf(pv[nb][j]);
        #pragma unroll
        for (int kk = 0; kk < 2; ++kk) {
            s16x8 pa = *(const s16x8*)&Pl[w][lr * PSTR + kk * 32 + g * 8];
            #pragma unroll
            for (int dn = 0; dn < 8; ++dn) {
                s16x8 bv = *(const s16x8*)&Vts[(dn * 16 + lr) * 72 + kk * 32 + g * 8];
                acc_o[dn] = __builtin_amdgcn_mfma_f32_16x16x32_bf16(pa, bv, acc_o[dn], 0, 0, 0);
            }
        }
    }

    float il[4];
    #pragma unroll
    for (int j = 0; j < 4; ++j) il[j] = 1.0f / ls[j];
    #pragma unroll
    for (int dn = 0; dn < 8; ++dn)
        #pragma unroll
        for (int j = 0; j < 4; ++j) {
            int q = q0 + w * 16 + g * 4 + j;
            Yb[(size_t)(b * SEQ + q) * D_MODEL + h * HDIM + dn * 16 + lr] =
                f2bf(acc_o[dn][j] * il[j]);
        }
}

// ---------------------------------------------------------------------------
extern "C" void kernel_launch(void* const* d_in, const int* in_sizes, int n_in,
                              void* d_out, int out_size, void* d_ws, size_t ws_size,
                              hipStream_t stream)
{
    const int*   tokens = (const int*)  d_in[0];
    const float* emb    = (const float*)d_in[1];
    const float* Wqkv   = (const float*)d_in[2];
    const float* bqkv   = (const float*)d_in[3];
    const float* Wo     = (const float*)d_in[4];
    const float* bo     = (const float*)d_in[5];
    const float* ln1_g  = (const float*)d_in[6];
    const float* ln1_b  = (const float*)d_in[7];
    const float* ln2_g  = (const float*)d_in[8];
    const float* ln2_b  = (const float*)d_in[9];
    const float* W1     = (const float*)d_in[10];
    const float* b1     = (const float*)d_in[11];
    const float* W2     = (const float*)d_in[12];
    const float* b2     = (const float*)d_in[13];
    const float* lnf_g  = (const float*)d_in[14];
    const float* lnf_b  = (const float*)d_in[15];
    const float* Wout   = (const float*)d_in[16];
    const float* bout   = (const float*)d_in[17];
    float* out = (float*)d_out;

    char* ws = (char*)d_ws;
    float*    X      = (float*)ws;                     // 16.78 MB
    ushort_t* Abuf   = (ushort_t*)(ws + 16777216);     // 8.39 MB
    ushort_t* QKVb   = (ushort_t*)(ws + 25165824);     // 25.17 MB
    ushort_t* Gbuf   = (ushort_t*)(ws + 25165824);     //   alias (FFN phase)
    ushort_t* Qbb    = (ushort_t*)(ws + 50331648);     // 8.39 MB
    ushort_t* Kbb    = (ushort_t*)(ws + 58720256);     // 8.39 MB
    ushort_t* Vtb    = (ushort_t*)(ws + 67108864);     // 8.39 MB
    ushort_t* WqkvT  = (ushort_t*)(ws + 75497472);     // 25.17 MB
    ushort_t* WoT    = (ushort_t*)(ws + 100663296);    // 8.39 MB
    ushort_t* W1T    = (ushort_t*)(ws + 109051904);    // 16.78 MB
    ushort_t* W2T    = (ushort_t*)(ws + 125829120);    // 16.78 MB
    ushort_t* WoutT  = (ushort_t*)(ws + 142606336);    // 65.54 MB -> 208.1 MB total

    const int M = MROWS, Dm = D_MODEL, F = FFN, V = VOCAB;

    wconv<<<dim3(3*Dm/32, Dm/32, NLAYER), 256, 0, stream>>>(Wqkv, WqkvT, Dm, 3*Dm);
    wconv<<<dim3(Dm/32,   Dm/32, NLAYER), 256, 0, stream>>>(Wo,   WoT,   Dm, Dm);
    wconv<<<dim3(F/32,    Dm/32, NLAYER), 256, 0, stream>>>(W1,   W1T,   Dm, F);
    wconv<<<dim3(Dm/32,   F/32,  NLAYER), 256, 0, stream>>>(W2,   W2T,   F,  Dm);
    wconv<<<dim3(V/32,    Dm/32, 1),      256, 0, stream>>>(Wout, WoutT, Dm, V);

    embed_kernel<<<MROWS, 256, 0, stream>>>(tokens, emb, X);

    for (int L = 0; L < NLAYER; ++L) {
        ln_kernel<<<MROWS, 256, 0, stream>>>(X, ln1_g + (size_t)L*Dm, ln1_b + (size_t)L*Dm, Abuf);
        gemm_mfma<0,0,1><<<dim3(M/128, 3*Dm/128), 256, 0, stream>>>(
            Abuf, WqkvT + (size_t)L*3*Dm*Dm, bqkv + (size_t)L*3*Dm, nullptr, QKVb, M, 3*Dm, Dm);
        ropeq_kernel<<<MROWS, 256, 0, stream>>>(QKVb, Qbb, Kbb);
        vtrans_kernel<<<dim3(SEQ/64, Dm/32, BATCH), 256, 0, stream>>>(QKVb, Vtb);
        attn_mfma<<<BATCH*NHEAD*(SEQ/64), 256, 0, stream>>>(Qbb, Kbb, Vtb, Abuf);
        gemm_mfma<0,1,0><<<dim3(M/128, Dm/128), 256, 0, stream>>>(
            Abuf, WoT + (size_t)L*Dm*Dm, bo + (size_t)L*Dm, X, nullptr, M, Dm, Dm);
        ln_kernel<<<MROWS, 256, 0, stream>>>(X, ln2_g + (size_t)L*Dm, ln2_b + (size_t)L*Dm, Abuf);
        gemm_mfma<1,0,1><<<dim3(M/128, F/128), 256, 0, stream>>>(
            Abuf, W1T + (size_t)L*Dm*F, b1 + (size_t)L*F, nullptr, Gbuf, M, F, Dm);
        gemm_mfma<0,1,0><<<dim3(M/128, Dm/128), 256, 0, stream>>>(
            Gbuf, W2T + (size_t)L*F*Dm, b2 + (size_t)L*Dm, X, nullptr, M, Dm, F);
    }

    ln_kernel<<<MROWS, 256, 0, stream>>>(X, lnf_g, lnf_b, Abuf);
    gemm_mfma<0,0,0><<<dim3(M/128, V/128), 256, 0, stream>>>(
        Abuf, WoutT, bout, out, nullptr, M, V, Dm);
}